// Round 1
// baseline (1188.882 us; speedup 1.0000x reference)
//
#include <hip/hip_runtime.h>
#include <hip/hip_bf16.h>

// Qwen3VL vision-language cross-attention block, MI355X/gfx950.
// Pipeline: cast6(wqkv->bf16, Q*scale*log2e) -> prep(pos+rmsnorm) ->
//   gemm<0> qkv (writes Q,K [t][4096] + V^T [b,h,d,t]) x2 -> cast3(proj w) ->
//   attn v2l (writes v2l_attn f32 + ctx bf16) -> attn l2v ->
//   gemm<1> ctx-proj (+residual, f32 out + bf16 mirror) x2 -> gemm<2> final.
// Workspace: 151.0 MB (overlays: ctx reuses wcat_v, proj weights reuse wcat_l).

typedef __bf16 b8 __attribute__((ext_vector_type(8)));
typedef float f4 __attribute__((ext_vector_type(4)));
typedef float f16v __attribute__((ext_vector_type(16)));
typedef unsigned int uint32;

#define MFMA_16(a,b,c) __builtin_amdgcn_mfma_f32_16x16x32_bf16(a,b,c,0,0,0)
#define MFMA_32(a,b,c) __builtin_amdgcn_mfma_f32_32x32x16_bf16(a,b,c,0,0,0)

__device__ __forceinline__ ushort f2bf(float f){
  uint32 u = __float_as_uint(f);
  return (ushort)((u + 0x7FFFu + ((u >> 16) & 1u)) >> 16);
}

__device__ __forceinline__ void async16(const void* g, void* l){
  __builtin_amdgcn_global_load_lds(
      (__attribute__((address_space(1))) void*)(g),
      (__attribute__((address_space(3))) void*)(l), 16, 0, 0);
}

__device__ __forceinline__ uint32 cvtpk(float a, float b){
  uint32 r;
  asm("v_cvt_pk_bf16_f32 %0, %1, %2" : "=v"(r) : "v"(a), "v"(b));
  return r;
}

// ---------------- weight cast (f32 -> bf16, optional scale) ----------------
struct CastArgs { const float* s[6]; ushort* d[6]; float sc[6]; int nseg; };

__global__ __launch_bounds__(256)
void cast_k(CastArgs a){
  int n = a.nseg << 20;   // segments of 2048*2048/4 = 1,048,576 float4
  for (int i = blockIdx.x*blockDim.x + threadIdx.x; i < n; i += gridDim.x*blockDim.x){
    int seg = i >> 20, off = i & 1048575;
    float4 v = reinterpret_cast<const float4*>(a.s[seg])[off];
    float sc = a.sc[seg];
    ushort4 o;
    o.x = f2bf(v.x*sc); o.y = f2bf(v.y*sc); o.z = f2bf(v.z*sc); o.w = f2bf(v.w*sc);
    reinterpret_cast<ushort4*>(a.d[seg])[off] = o;
  }
}

// ---------------- pos-embed add + RMSNorm ----------------
__global__ __launch_bounds__(256)
void prep_k(const float* __restrict__ vfeat, const float* __restrict__ lfeat,
            const float* __restrict__ vpos, const float* __restrict__ lpos,
            const float* __restrict__ vw, const float* __restrict__ lw,
            float* __restrict__ vfo, float* __restrict__ lfo,
            ushort* __restrict__ vnb, ushort* __restrict__ lnb)
{
  const int row = blockIdx.x;   // 0..6143 (2048 vision rows, then 4096 language)
  const float *src, *pos, *w;
  float* fo; ushort* nb;
  if (row < 2048){
    src = vfeat + (size_t)row*2048; pos = vpos + (size_t)(row & 1023)*2048;
    w = vw; fo = vfo + (size_t)row*2048; nb = vnb + (size_t)row*2048;
  } else {
    int r = row - 2048;
    src = lfeat + (size_t)r*2048; pos = lpos + (size_t)(r & 2047)*2048;
    w = lw; fo = lfo + (size_t)r*2048; nb = lnb + (size_t)r*2048;
  }
  const int t = threadIdx.x;
  float4 a0 = reinterpret_cast<const float4*>(src)[t];
  float4 p0 = reinterpret_cast<const float4*>(pos)[t];
  float4 a1 = reinterpret_cast<const float4*>(src)[t+256];
  float4 p1 = reinterpret_cast<const float4*>(pos)[t+256];
  a0.x += p0.x; a0.y += p0.y; a0.z += p0.z; a0.w += p0.w;
  a1.x += p1.x; a1.y += p1.y; a1.z += p1.z; a1.w += p1.w;
  float ss = a0.x*a0.x + a0.y*a0.y + a0.z*a0.z + a0.w*a0.w
           + a1.x*a1.x + a1.y*a1.y + a1.z*a1.z + a1.w*a1.w;
  #pragma unroll
  for (int o = 32; o > 0; o >>= 1) ss += __shfl_xor(ss, o, 64);
  __shared__ float red[4];
  if ((t & 63) == 0) red[t >> 6] = ss;
  __syncthreads();
  float rs = rsqrtf((red[0]+red[1]+red[2]+red[3]) * (1.0f/2048.0f) + 1e-6f);
  reinterpret_cast<float4*>(fo)[t]     = a0;
  reinterpret_cast<float4*>(fo)[t+256] = a1;
  float4 w0 = reinterpret_cast<const float4*>(w)[t];
  float4 w1 = reinterpret_cast<const float4*>(w)[t+256];
  ushort4 o0, o1;
  o0.x = f2bf(a0.x*rs*w0.x); o0.y = f2bf(a0.y*rs*w0.y);
  o0.z = f2bf(a0.z*rs*w0.z); o0.w = f2bf(a0.w*rs*w0.w);
  o1.x = f2bf(a1.x*rs*w1.x); o1.y = f2bf(a1.y*rs*w1.y);
  o1.z = f2bf(a1.z*rs*w1.z); o1.w = f2bf(a1.w*rs*w1.w);
  reinterpret_cast<ushort4*>(nb)[t]     = o0;
  reinterpret_cast<ushort4*>(nb)[t+256] = o1;
}

// ---------------- NT GEMM, m97 structure: 128x128 tile, BK=32 ----------------
// MODE 0: QKV. cols<4096 -> bf16 to OB (ld 4096). cols>=4096 -> V, stored
//         TRANSPOSED into VT[b,h,d,t] (T = 1<<logT rows/batch).
// MODE 1: ctx proj: f32 out = acc + OF[idx] (residual, in-place on d_out
//         section), plus bf16 mirror to OB (ld 2048).
// MODE 2: final proj: A rows are fused concat (A=vision bf16, A2=language bf16),
//         f32 out only.
template<int MODE>
__global__ __launch_bounds__(256, 3)
void gemm_k(const ushort* __restrict__ A, const ushort* __restrict__ A2,
            const ushort* __restrict__ W, ushort* __restrict__ OB,
            ushort* __restrict__ VT, float* __restrict__ OF, int logT)
{
  __shared__ __align__(16) ushort As[4096];
  __shared__ __align__(16) ushort Bs[4096];
  const int tid = threadIdx.x;
  const int l = tid & 63, wid = tid >> 6;
  const int wm = (wid >> 1) * 64, wn = (wid & 1) * 64;
  const int m0 = blockIdx.y * 128, n0 = blockIdx.x * 128;
  const int lr = l & 15, lk = l >> 4;
  f4 acc[4][4] = {};
  for (int kt = 0; kt < 2048; kt += 32) {
    #pragma unroll
    for (int i = 0; i < 2; ++i){
      int c = wid*64 + l + i*256;
      int row = c >> 2, kc = (c & 3) * 8;
      const ushort* ga;
      if constexpr (MODE == 2) {
        int f = m0 + row;
        int bb = (f >= 3072) ? 1 : 0;
        int rr = f - bb*3072;
        ga = (rr < 1024) ? (A  + ((size_t)(bb*1024 + rr))*2048 + kt + kc)
                         : (A2 + ((size_t)(bb*2048 + rr - 1024))*2048 + kt + kc);
      } else {
        ga = A + (size_t)(m0 + row)*2048 + kt + kc;
      }
      async16(ga, &As[c*8]);
      async16(W + (size_t)(n0 + row)*2048 + kt + kc, &Bs[c*8]);
    }
    __syncthreads();
    b8 af[4], bfr[4];
    #pragma unroll
    for (int i = 0; i < 4; ++i)
      af[i] = *reinterpret_cast<const b8*>(&As[(wm + i*16 + lr)*32 + lk*8]);
    #pragma unroll
    for (int j = 0; j < 4; ++j)
      bfr[j] = *reinterpret_cast<const b8*>(&Bs[(wn + j*16 + lr)*32 + lk*8]);
    #pragma unroll
    for (int i = 0; i < 4; ++i)
      #pragma unroll
      for (int j = 0; j < 4; ++j)
        acc[i][j] = MFMA_16(af[i], bfr[j], acc[i][j]);
    __syncthreads();
  }
  #pragma unroll
  for (int i = 0; i < 4; ++i){
    int row0 = m0 + wm + i*16 + lk*4;
    #pragma unroll
    for (int j = 0; j < 4; ++j){
      int col = n0 + wn + j*16 + lr;
      if constexpr (MODE == 0){
        if (col < 4096){
          #pragma unroll
          for (int r = 0; r < 4; ++r)
            OB[(size_t)(row0 + r)*4096 + col] = f2bf(acc[i][j][r]);
        } else {
          int d = col - 4096, hh = d >> 7, dd = d & 127;
          int bb = row0 >> logT;
          int t0 = row0 - (bb << logT);
          ushort4 pk;
          pk.x = f2bf(acc[i][j][0]); pk.y = f2bf(acc[i][j][1]);
          pk.z = f2bf(acc[i][j][2]); pk.w = f2bf(acc[i][j][3]);
          *reinterpret_cast<ushort4*>(
              &VT[(((size_t)(bb*16 + hh)*128 + dd) << logT) + t0]) = pk;
        }
      } else if constexpr (MODE == 1){
        #pragma unroll
        for (int r = 0; r < 4; ++r){
          size_t idx = (size_t)(row0 + r)*2048 + col;
          float v = acc[i][j][r] + OF[idx];
          OF[idx] = v;
          OB[idx] = f2bf(v);
        }
      } else {
        #pragma unroll
        for (int r = 0; r < 4; ++r)
          OF[(size_t)(row0 + r)*2048 + col] = acc[i][j][r];
      }
    }
  }
}

// ---------------- fused cross-attention ----------------
// Swapped QK^T: mfma(A=K, B=Q) -> lane owns q-col (l&31), 16 s-rows in regs.
// Two passes over KV: pass1 = running (max,sum) in log2 domain (Q weights were
// pre-scaled by SCALE*log2e), pass2 = recompute scores, write normalized attn
// (WA) + PV with cvt_pk + shfl_xor(32) register redistribution of P.
// K tile LDS [32s][16 gran] with gran XOR (s&15); V^T tile LDS [128d][4 gran]
// with gran XOR (d&3): staging is linear global_load_lds, frag reads XOR back.
template<int SKV, int WARPS, bool WA>
__global__ __launch_bounds__(WARPS*64, 2)
void attn_k(const ushort* __restrict__ qbuf, const ushort* __restrict__ kbuf,
            const ushort* __restrict__ vtb, float* __restrict__ attn,
            ushort* __restrict__ ctx, int TQ)
{
  constexpr int NT = SKV / 32;
  constexpr int NI = 512 / (WARPS*64);
  __shared__ __align__(16) ushort Ks[2][4096];
  __shared__ __align__(16) ushort Vs[2][4096];
  __shared__ __align__(16) float ast[WA ? WARPS*32*36 : 4];
  __shared__ float linv[WARPS*32];
  const int tid = threadIdx.x;
  const int l = tid & 63, wid = tid >> 6;
  const int hi = l >> 5, q = l & 31;
  const int b = blockIdx.z, h = blockIdx.y;
  const int q0 = blockIdx.x*(WARPS*32) + wid*32;     // q base within batch
  const ushort* kbase = kbuf + (size_t)b*SKV*4096 + 2048 + h*128;
  const ushort* vbase = vtb + ((size_t)(b*16 + h))*128*SKV;

  b8 qf[8];
  {
    const ushort* qp = qbuf + (size_t)(b*TQ + q0 + q)*4096 + h*128 + hi*8;
    #pragma unroll
    for (int kd = 0; kd < 8; ++kd)
      qf[kd] = *reinterpret_cast<const b8*>(qp + kd*16);
  }

  #define STK(tt, bi) { int S0_ = (tt)*32; _Pragma("unroll") \
    for (int i_ = 0; i_ < NI; ++i_){ \
      int c_ = wid*64 + l + i_*(WARPS*64); int s_ = c_>>4, g_ = c_&15; \
      async16(kbase + (size_t)(S0_+s_)*4096 + (g_^(s_&15))*8, &Ks[bi][c_*8]); } }
  #define STV(tt, bi) { int S0_ = (tt)*32; _Pragma("unroll") \
    for (int i_ = 0; i_ < NI; ++i_){ \
      int c_ = wid*64 + l + i_*(WARPS*64); int d_ = c_>>2, g_ = c_&3; \
      async16(vbase + (size_t)d_*SKV + S0_ + (g_^(d_&3))*8, &Vs[bi][c_*8]); } }

  // ---- pass 1: stats ----
  float mrun = -1e30f, lrun = 0.0f;
  STK(0, 0);
  for (int t = 0; t < NT; ++t){
    __syncthreads();
    if (t+1 < NT) STK(t+1, (t+1)&1);
    f16v s16 = {};
    #pragma unroll
    for (int kd = 0; kd < 8; ++kd){
      int gg = (kd*2 + hi) ^ (q & 15);
      b8 kf = *reinterpret_cast<const b8*>(&Ks[t&1][q*128 + gg*8]);
      s16 = MFMA_32(kf, qf[kd], s16);
    }
    float tm = s16[0];
    #pragma unroll
    for (int r = 1; r < 16; ++r) tm = fmaxf(tm, s16[r]);
    float mnew = fmaxf(mrun, tm);
    float sum = 0.f;
    #pragma unroll
    for (int r = 0; r < 16; ++r) sum += exp2f(s16[r] - mnew);
    lrun = lrun * exp2f(mrun - mnew) + sum;
    mrun = mnew;
  }
  {
    float mo = __shfl_xor(mrun, 32, 64);
    float lo = __shfl_xor(lrun, 32, 64);
    float mf = fmaxf(mrun, mo);
    lrun = lrun * exp2f(mrun - mf) + lo * exp2f(mo - mf);
    mrun = mf;
  }
  float invl = 1.0f / lrun;
  if (hi == 0) linv[wid*32 + q] = invl;
  __syncthreads();          // pass1 reads done before pass2 staging overwrites
  STK(0, 0); STV(0, 0);

  // ---- pass 2: attn write + PV ----
  f16v O[4] = {};
  for (int t = 0; t < NT; ++t){
    __syncthreads();
    if (t+1 < NT){ STK(t+1, (t+1)&1); STV(t+1, (t+1)&1); }
    const int bi = t & 1;
    f16v s16 = {};
    #pragma unroll
    for (int kd = 0; kd < 8; ++kd){
      int gg = (kd*2 + hi) ^ (q & 15);
      b8 kf = *reinterpret_cast<const b8*>(&Ks[bi][q*128 + gg*8]);
      s16 = MFMA_32(kf, qf[kd], s16);
    }
    float e[16];
    #pragma unroll
    for (int r = 0; r < 16; ++r) e[r] = exp2f(s16[r] - mrun);
    if constexpr (WA){
      float* myt = &ast[wid*32*36];    // warp-private [32 q][36 pad] f32
      #pragma unroll
      for (int r = 0; r < 16; ++r){
        int sr = (r&3) + 8*(r>>2) + 4*hi;
        myt[q*36 + sr] = e[r] * invl;
      }
    }
    #pragma unroll
    for (int ks = 0; ks < 2; ++ks){
      const int base = ks*8;
      uint32 A0 = cvtpk(e[base+0], e[base+1]);
      uint32 A1 = cvtpk(e[base+2], e[base+3]);
      uint32 B0 = cvtpk(e[base+4], e[base+5]);
      uint32 B1 = cvtpk(e[base+6], e[base+7]);
      uint32 A0x = (uint32)__shfl_xor((int)A0, 32, 64);
      uint32 A1x = (uint32)__shfl_xor((int)A1, 32, 64);
      uint32 B0x = (uint32)__shfl_xor((int)B0, 32, 64);
      uint32 B1x = (uint32)__shfl_xor((int)B1, 32, 64);
      uint4 ww;
      ww.x = hi ? B0x : A0;
      ww.y = hi ? B1x : A1;
      ww.z = hi ? B0  : A0x;
      ww.w = hi ? B1  : A1x;
      b8 pa = __builtin_bit_cast(b8, ww);
      #pragma unroll
      for (int nb = 0; nb < 4; ++nb){
        int d = nb*32 + q;
        int gg2 = (ks*2 + hi) ^ (d & 3);
        b8 vfr = *reinterpret_cast<const b8*>(&Vs[bi][d*32 + gg2*8]);
        O[nb] = MFMA_32(pa, vfr, O[nb]);
      }
    }
    if constexpr (WA){
      const float* myt = &ast[wid*32*36];
      size_t abase = ((size_t)(b*16 + h)*TQ + q0) * SKV + t*32;
      #pragma unroll
      for (int it = 0; it < 4; ++it){
        int qq = (l >> 3) + it*8;
        float4 vv = *reinterpret_cast<const float4*>(&myt[qq*36 + (l&7)*4]);
        *reinterpret_cast<float4*>(&attn[abase + (size_t)qq*SKV + (l&7)*4]) = vv;
      }
    }
  }
  #pragma unroll
  for (int nb = 0; nb < 4; ++nb){
    #pragma unroll
    for (int r = 0; r < 16; ++r){
      int lq = (r&3) + 8*(r>>2) + 4*hi;
      float val = O[nb][r] * linv[wid*32 + lq];
      ctx[(size_t)(b*TQ + q0 + lq)*2048 + h*128 + nb*32 + q] = f2bf(val);
    }
  }
  #undef STK
  #undef STV
}

// ---------------- host ----------------
extern "C" void kernel_launch(void* const* d_in, const int* in_sizes, int n_in,
                              void* d_out, int out_size, void* d_ws, size_t ws_size,
                              hipStream_t stream)
{
  (void)in_sizes; (void)n_in; (void)out_size; (void)ws_size;
  const float* vfeat = (const float*)d_in[0];
  const float* lfeat = (const float*)d_in[1];
  const float* vpos  = (const float*)d_in[2];
  const float* lpos  = (const float*)d_in[3];
  const float* vw    = (const float*)d_in[4];
  const float* lw    = (const float*)d_in[5];
  const float* w_vq  = (const float*)d_in[6];
  const float* w_vk  = (const float*)d_in[7];
  const float* w_vv  = (const float*)d_in[8];
  const float* w_lq  = (const float*)d_in[9];
  const float* w_lk  = (const float*)d_in[10];
  const float* w_lv  = (const float*)d_in[11];
  const float* w_v2l = (const float*)d_in[12];
  const float* w_l2v = (const float*)d_in[13];
  const float* w_out = (const float*)d_in[14];

  float* out     = (float*)d_out;
  float* fused_o = out;                 // [2,3072,2048]
  float* vis_o   = out + 12582912;      // [2,1024,2048]
  float* lan_o   = out + 16777216;      // [2,2048,2048]
  float* attn_o  = out + 25165824;      // [2,16,1024,2048]

  ushort* ws = (ushort*)d_ws;           // total 75,497,472 ushorts = 151.0 MB
  ushort* wcat_v = ws;                        // [6144][2048] bf16
  ushort* wcat_l = wcat_v + 12582912;         // [6144][2048]
  ushort* vnb    = wcat_l + 12582912;         // [2048][2048] norm'd vision / later vision_out bf16
  ushort* lnb    = vnb + 4194304;             // [4096][2048]
  ushort* vqk    = lnb + 8388608;             // [2048][4096] (Q|K)
  ushort* lqk    = vqk + 8388608;             // [4096][4096]
  ushort* vtv    = lqk + 16777216;            // [2,16,128,1024] V^T vision
  ushort* vtl    = vtv + 4194304;             // [2,16,128,2048] V^T language
  // overlays (lifetimes disjoint):
  ushort* vctx    = wcat_v;                   // [2048][2048] after vision QKV GEMM
  ushort* lctx    = wcat_v + 4194304;         // [4096][2048]
  ushort* w_v2l_b = wcat_l;                   // after language QKV GEMM
  ushort* w_l2v_b = wcat_l + 4194304;
  ushort* w_out_b = wcat_l + 8388608;

  const float QS = 0.08838834764831845f * 1.4426950408889634f; // SCALE * log2(e)

  {
    CastArgs a;
    a.s[0]=w_vq; a.d[0]=wcat_v;           a.sc[0]=QS;
    a.s[1]=w_vk; a.d[1]=wcat_v+4194304;   a.sc[1]=1.f;
    a.s[2]=w_vv; a.d[2]=wcat_v+8388608;   a.sc[2]=1.f;
    a.s[3]=w_lq; a.d[3]=wcat_l;           a.sc[3]=QS;
    a.s[4]=w_lk; a.d[4]=wcat_l+4194304;   a.sc[4]=1.f;
    a.s[5]=w_lv; a.d[5]=wcat_l+8388608;   a.sc[5]=1.f;
    a.nseg = 6;
    cast_k<<<2048,256,0,stream>>>(a);
  }
  prep_k<<<6144,256,0,stream>>>(vfeat,lfeat,vpos,lpos,vw,lw,vis_o,lan_o,vnb,lnb);
  gemm_k<0><<<dim3(48,16),256,0,stream>>>(vnb,nullptr,wcat_v,vqk,vtv,nullptr,10);
  gemm_k<0><<<dim3(48,32),256,0,stream>>>(lnb,nullptr,wcat_l,lqk,vtl,nullptr,11);
  {
    CastArgs a;
    a.s[0]=w_v2l; a.d[0]=w_v2l_b; a.sc[0]=1.f;
    a.s[1]=w_l2v; a.d[1]=w_l2v_b; a.sc[1]=1.f;
    a.s[2]=w_out; a.d[2]=w_out_b; a.sc[2]=1.f;
    a.nseg = 3;
    cast_k<<<2048,256,0,stream>>>(a);
  }
  attn_k<2048,4,true ><<<dim3( 8,16,2),256,0,stream>>>(vqk,lqk,vtl,attn_o,vctx,1024);
  attn_k<1024,4,false><<<dim3(16,16,2),256,0,stream>>>(lqk,vqk,vtv,nullptr,lctx,2048);
  gemm_k<1><<<dim3(16,16),256,0,stream>>>(vctx,nullptr,w_v2l_b,vnb,nullptr,vis_o,0);
  gemm_k<1><<<dim3(16,32),256,0,stream>>>(lctx,nullptr,w_l2v_b,lnb,nullptr,lan_o,0);
  gemm_k<2><<<dim3(16,48),256,0,stream>>>(vnb,lnb,w_out_b,nullptr,nullptr,fused_o,0);
}

// Round 2
// 1181.078 us; speedup vs baseline: 1.0066x; 1.0066x over previous
//
#include <hip/hip_runtime.h>
#include <hip/hip_bf16.h>

// Qwen3VL vision-language cross-attention block, MI355X/gfx950.
// R1: big GEMMs (QKV x2, final) moved to 256x256 8-phase template
// (T1 XCD swizzle + T2 LDS swizzle + T3/T4 counted vmcnt + T5 setprio).
// ctx-proj GEMMs stay on 128^2 m97 structure; attn unchanged.

typedef __bf16 b8 __attribute__((ext_vector_type(8)));
typedef float f4 __attribute__((ext_vector_type(4)));
typedef float f16v __attribute__((ext_vector_type(16)));
typedef unsigned int uint32;

#define MFMA_16(a,b,c) __builtin_amdgcn_mfma_f32_16x16x32_bf16(a,b,c,0,0,0)
#define MFMA_32(a,b,c) __builtin_amdgcn_mfma_f32_32x32x16_bf16(a,b,c,0,0,0)

__device__ __forceinline__ ushort f2bf(float f){
  uint32 u = __float_as_uint(f);
  return (ushort)((u + 0x7FFFu + ((u >> 16) & 1u)) >> 16);
}

__device__ __forceinline__ void async16(const void* g, void* l){
  __builtin_amdgcn_global_load_lds(
      (__attribute__((address_space(1))) void*)(g),
      (__attribute__((address_space(3))) void*)(l), 16, 0, 0);
}

__device__ __forceinline__ uint32 cvtpk(float a, float b){
  uint32 r;
  asm("v_cvt_pk_bf16_f32 %0, %1, %2" : "=v"(r) : "v"(a), "v"(b));
  return r;
}

// ---------------- weight cast (f32 -> bf16, optional scale) ----------------
struct CastArgs { const float* s[6]; ushort* d[6]; float sc[6]; int nseg; };

__global__ __launch_bounds__(256)
void cast_k(CastArgs a){
  int n = a.nseg << 20;
  for (int i = blockIdx.x*blockDim.x + threadIdx.x; i < n; i += gridDim.x*blockDim.x){
    int seg = i >> 20, off = i & 1048575;
    float4 v = reinterpret_cast<const float4*>(a.s[seg])[off];
    float sc = a.sc[seg];
    ushort4 o;
    o.x = f2bf(v.x*sc); o.y = f2bf(v.y*sc); o.z = f2bf(v.z*sc); o.w = f2bf(v.w*sc);
    reinterpret_cast<ushort4*>(a.d[seg])[off] = o;
  }
}

// ---------------- pos-embed add + RMSNorm ----------------
__global__ __launch_bounds__(256)
void prep_k(const float* __restrict__ vfeat, const float* __restrict__ lfeat,
            const float* __restrict__ vpos, const float* __restrict__ lpos,
            const float* __restrict__ vw, const float* __restrict__ lw,
            float* __restrict__ vfo, float* __restrict__ lfo,
            ushort* __restrict__ vnb, ushort* __restrict__ lnb)
{
  const int row = blockIdx.x;
  const float *src, *pos, *w;
  float* fo; ushort* nb;
  if (row < 2048){
    src = vfeat + (size_t)row*2048; pos = vpos + (size_t)(row & 1023)*2048;
    w = vw; fo = vfo + (size_t)row*2048; nb = vnb + (size_t)row*2048;
  } else {
    int r = row - 2048;
    src = lfeat + (size_t)r*2048; pos = lpos + (size_t)(r & 2047)*2048;
    w = lw; fo = lfo + (size_t)r*2048; nb = lnb + (size_t)r*2048;
  }
  const int t = threadIdx.x;
  float4 a0 = reinterpret_cast<const float4*>(src)[t];
  float4 p0 = reinterpret_cast<const float4*>(pos)[t];
  float4 a1 = reinterpret_cast<const float4*>(src)[t+256];
  float4 p1 = reinterpret_cast<const float4*>(pos)[t+256];
  a0.x += p0.x; a0.y += p0.y; a0.z += p0.z; a0.w += p0.w;
  a1.x += p1.x; a1.y += p1.y; a1.z += p1.z; a1.w += p1.w;
  float ss = a0.x*a0.x + a0.y*a0.y + a0.z*a0.z + a0.w*a0.w
           + a1.x*a1.x + a1.y*a1.y + a1.z*a1.z + a1.w*a1.w;
  #pragma unroll
  for (int o = 32; o > 0; o >>= 1) ss += __shfl_xor(ss, o, 64);
  __shared__ float red[4];
  if ((t & 63) == 0) red[t >> 6] = ss;
  __syncthreads();
  float rs = rsqrtf((red[0]+red[1]+red[2]+red[3]) * (1.0f/2048.0f) + 1e-6f);
  reinterpret_cast<float4*>(fo)[t]     = a0;
  reinterpret_cast<float4*>(fo)[t+256] = a1;
  float4 w0 = reinterpret_cast<const float4*>(w)[t];
  float4 w1 = reinterpret_cast<const float4*>(w)[t+256];
  ushort4 o0, o1;
  o0.x = f2bf(a0.x*rs*w0.x); o0.y = f2bf(a0.y*rs*w0.y);
  o0.z = f2bf(a0.z*rs*w0.z); o0.w = f2bf(a0.w*rs*w0.w);
  o1.x = f2bf(a1.x*rs*w1.x); o1.y = f2bf(a1.y*rs*w1.y);
  o1.z = f2bf(a1.z*rs*w1.z); o1.w = f2bf(a1.w*rs*w1.w);
  reinterpret_cast<ushort4*>(nb)[t]     = o0;
  reinterpret_cast<ushort4*>(nb)[t+256] = o1;
}

// ---------------- 128x128 m97 GEMM (kept for ctx-proj, MODE 1) ----------------
template<int MODE>
__global__ __launch_bounds__(256, 3)
void gemm_k(const ushort* __restrict__ A, const ushort* __restrict__ A2,
            const ushort* __restrict__ W, ushort* __restrict__ OB,
            ushort* __restrict__ VT, float* __restrict__ OF, int logT)
{
  __shared__ __align__(16) ushort As[4096];
  __shared__ __align__(16) ushort Bs[4096];
  const int tid = threadIdx.x;
  const int l = tid & 63, wid = tid >> 6;
  const int wm = (wid >> 1) * 64, wn = (wid & 1) * 64;
  const int m0 = blockIdx.y * 128, n0 = blockIdx.x * 128;
  const int lr = l & 15, lk = l >> 4;
  f4 acc[4][4] = {};
  for (int kt = 0; kt < 2048; kt += 32) {
    #pragma unroll
    for (int i = 0; i < 2; ++i){
      int c = wid*64 + l + i*256;
      int row = c >> 2, kc = (c & 3) * 8;
      const ushort* ga = A + (size_t)(m0 + row)*2048 + kt + kc;
      async16(ga, &As[c*8]);
      async16(W + (size_t)(n0 + row)*2048 + kt + kc, &Bs[c*8]);
    }
    __syncthreads();
    b8 af[4], bfr[4];
    #pragma unroll
    for (int i = 0; i < 4; ++i)
      af[i] = *reinterpret_cast<const b8*>(&As[(wm + i*16 + lr)*32 + lk*8]);
    #pragma unroll
    for (int j = 0; j < 4; ++j)
      bfr[j] = *reinterpret_cast<const b8*>(&Bs[(wn + j*16 + lr)*32 + lk*8]);
    #pragma unroll
    for (int i = 0; i < 4; ++i)
      #pragma unroll
      for (int j = 0; j < 4; ++j)
        acc[i][j] = MFMA_16(af[i], bfr[j], acc[i][j]);
    __syncthreads();
  }
  #pragma unroll
  for (int i = 0; i < 4; ++i){
    int row0 = m0 + wm + i*16 + lk*4;
    #pragma unroll
    for (int j = 0; j < 4; ++j){
      int col = n0 + wn + j*16 + lr;
      #pragma unroll
      for (int r = 0; r < 4; ++r){
        size_t idx = (size_t)(row0 + r)*2048 + col;
        float v = acc[i][j][r] + OF[idx];
        OF[idx] = v;
        OB[idx] = f2bf(v);
      }
    }
  }
}

// ---------------- 256x256 8-phase GEMM (T1+T2+T3+T4+T5) ----------------
// BM=BN=256, BK=64, 512 thr = 8 waves (2M x 4N), per-wave C = 128x64.
// LDS 128 KiB: [2 buf][4 region: A0,A1,B0,B1][128 rows][64 cols] bf16,
// granule-swizzled (g ^= row&7) via pre-swizzled global source (rule #21).
// Per K-tile 4 phases; quadrants (M0N0, M0N1, M1N0, M1N1).
// Stage stream: ph0: A1(t+1); ph2: B0(t+2); ph3: B1(t+2), A0(t+2);
// single s_waitcnt vmcnt(6) per K-tile (3 half-tiles in flight).
// MODE 0: QKV epilogue (Q|K bf16 cols<4096; V transposed into VT[b,h,d,t]).
// MODE 2: final proj: A = concat(vision A, language A2), f32 out.
template<int MODE>
__global__ __launch_bounds__(512, 2)
void gemm8_k(const ushort* __restrict__ A, const ushort* __restrict__ A2,
             const ushort* __restrict__ W, ushort* __restrict__ OB,
             ushort* __restrict__ VT, float* __restrict__ OF, int logT)
{
  __shared__ __align__(16) ushort Ls[65536];   // 128 KiB
  const int tid = threadIdx.x;
  const int l = tid & 63, wid = tid >> 6;
  const int wmid = wid >> 2, wnid = wid & 3;
  const int lrow = l & 15, lg = l >> 4, lx = l & 7;

  // T1: bijective XCD swizzle (nwg % 8 == 0 for all our grids)
  const int nbx = gridDim.x;
  const int nwg = nbx * gridDim.y;
  const int wg  = blockIdx.y*nbx + blockIdx.x;
  const int swz = (wg & 7)*(nwg >> 3) + (wg >> 3);
  const int m0 = (swz / nbx) * 256, n0 = (swz % nbx) * 256;

  // per-thread stage sources (chunk c = tid + i*512; r = c>>3, gs = c&7)
  const ushort* srcA[2][2];       // [half][i]
  const ushort* srcB[2][2];
  int ldsOff[2];
  #pragma unroll
  for (int i = 0; i < 2; ++i){
    int c = tid + i*512;
    int r = c >> 3, gs = c & 7;
    int scol = (gs ^ (r & 7)) * 8;     // pre-swizzled source granule
    ldsOff[i] = c * 8;
    #pragma unroll
    for (int hh = 0; hh < 2; ++hh){
      int growA = m0 + hh*128 + r;
      const ushort* pa;
      if constexpr (MODE == 2){
        int bb = (growA >= 3072) ? 1 : 0;
        int rr = growA - bb*3072;
        pa = (rr < 1024) ? (A  + (size_t)(bb*1024 + rr)*2048)
                         : (A2 + (size_t)(bb*2048 + rr - 1024)*2048);
      } else {
        pa = A + (size_t)growA*2048;
      }
      srcA[hh][i] = pa + scol;
      srcB[hh][i] = W + (size_t)(n0 + hh*128 + r)*2048 + scol;
    }
  }

  #define STA8(hh, tt) { int bo_ = ((tt)&1)*32768; _Pragma("unroll") \
    for (int i_ = 0; i_ < 2; ++i_) \
      async16(srcA[hh][i_] + (tt)*64, &Ls[bo_ + (hh)*8192 + ldsOff[i_]]); }
  #define STB8(hh, tt) { int bo_ = ((tt)&1)*32768; _Pragma("unroll") \
    for (int i_ = 0; i_ < 2; ++i_) \
      async16(srcB[hh][i_] + (tt)*64, &Ls[bo_ + 16384 + (hh)*8192 + ldsOff[i_]]); }

  // read-side addressing (swizzle undone: g ^ lx)
  const int aBase = wmid*8192 + lrow*64;
  const int bBase = 16384 + (wnid>>1)*8192 + (wnid&1)*4096 + lrow*64;
  int gsw[2];
  gsw[0] = ((0*4 + lg) ^ lx) * 8;
  gsw[1] = ((1*4 + lg) ^ lx) * 8;

  constexpr int NT = 32;   // K = 2048 / BK = 64
  // prologue stream: B0(0),B1(0),A0(0),A1(0),B0(1),B1(1),A0(1)
  STB8(0,0); STB8(1,0); STA8(0,0); STA8(1,0); STB8(0,1); STB8(1,1); STA8(0,1);
  asm volatile("s_waitcnt vmcnt(6)" ::: "memory");
  __builtin_amdgcn_s_barrier();

  f4 acc[8][4] = {};
  b8 afr[4][2], b0r[2][2], b1r[2][2];

  for (int t = 0; t < NT; ++t){
    const ushort* Lb = &Ls[(t & 1) * 32768];
    // ---- phase 0: read A(ms0)+B(ns0), stage A1(t+1), MFMA Q(0,0) ----
    #pragma unroll
    for (int mi = 0; mi < 4; ++mi)
      #pragma unroll
      for (int kk = 0; kk < 2; ++kk)
        afr[mi][kk] = *reinterpret_cast<const b8*>(&Lb[aBase + mi*1024 + gsw[kk]]);
    #pragma unroll
    for (int nj = 0; nj < 2; ++nj)
      #pragma unroll
      for (int kk = 0; kk < 2; ++kk)
        b0r[nj][kk] = *reinterpret_cast<const b8*>(&Lb[bBase + nj*1024 + gsw[kk]]);
    if (t+1 < NT) STA8(1, t+1);
    __builtin_amdgcn_s_barrier();
    asm volatile("s_waitcnt lgkmcnt(0)" ::: "memory");
    __builtin_amdgcn_s_setprio(1);
    #pragma unroll
    for (int mi = 0; mi < 4; ++mi)
      #pragma unroll
      for (int nj = 0; nj < 2; ++nj)
        #pragma unroll
        for (int kk = 0; kk < 2; ++kk)
          acc[mi][nj] = MFMA_16(afr[mi][kk], b0r[nj][kk], acc[mi][nj]);
    __builtin_amdgcn_s_setprio(0);
    __builtin_amdgcn_s_barrier();
    // ---- phase 1: read B(ns1), MFMA Q(0,1) ----
    #pragma unroll
    for (int nj = 0; nj < 2; ++nj)
      #pragma unroll
      for (int kk = 0; kk < 2; ++kk)
        b1r[nj][kk] = *reinterpret_cast<const b8*>(&Lb[bBase + (2+nj)*1024 + gsw[kk]]);
    __builtin_amdgcn_s_barrier();
    asm volatile("s_waitcnt lgkmcnt(0)" ::: "memory");
    __builtin_amdgcn_s_setprio(1);
    #pragma unroll
    for (int mi = 0; mi < 4; ++mi)
      #pragma unroll
      for (int nj = 0; nj < 2; ++nj)
        #pragma unroll
        for (int kk = 0; kk < 2; ++kk)
          acc[mi][2+nj] = MFMA_16(afr[mi][kk], b1r[nj][kk], acc[mi][2+nj]);
    __builtin_amdgcn_s_setprio(0);
    __builtin_amdgcn_s_barrier();
    // ---- phase 2: read A(ms1), stage B0(t+2), MFMA Q(1,0) ----
    #pragma unroll
    for (int mi = 0; mi < 4; ++mi)
      #pragma unroll
      for (int kk = 0; kk < 2; ++kk)
        afr[mi][kk] = *reinterpret_cast<const b8*>(&Lb[aBase + 4096 + mi*1024 + gsw[kk]]);
    if (t+2 < NT) STB8(0, t+2);
    __builtin_amdgcn_s_barrier();
    asm volatile("s_waitcnt lgkmcnt(0)" ::: "memory");
    __builtin_amdgcn_s_setprio(1);
    #pragma unroll
    for (int mi = 0; mi < 4; ++mi)
      #pragma unroll
      for (int nj = 0; nj < 2; ++nj)
        #pragma unroll
        for (int kk = 0; kk < 2; ++kk)
          acc[4+mi][nj] = MFMA_16(afr[mi][kk], b0r[nj][kk], acc[4+mi][nj]);
    __builtin_amdgcn_s_setprio(0);
    __builtin_amdgcn_s_barrier();
    // ---- phase 3: stage B1(t+2)+A0(t+2), MFMA Q(1,1), vmcnt(6) ----
    if (t+2 < NT){ STB8(1, t+2); STA8(0, t+2); }
    __builtin_amdgcn_s_barrier();
    __builtin_amdgcn_s_setprio(1);
    #pragma unroll
    for (int mi = 0; mi < 4; ++mi)
      #pragma unroll
      for (int nj = 0; nj < 2; ++nj)
        #pragma unroll
        for (int kk = 0; kk < 2; ++kk)
          acc[4+mi][2+nj] = MFMA_16(afr[mi][kk], b1r[nj][kk], acc[4+mi][2+nj]);
    __builtin_amdgcn_s_setprio(0);
    if (t+2 < NT){ asm volatile("s_waitcnt vmcnt(6)" ::: "memory"); }
    else         { asm volatile("s_waitcnt vmcnt(0)" ::: "memory"); }
    __builtin_amdgcn_s_barrier();
  }

  // ---- epilogue ----
  #pragma unroll
  for (int mi = 0; mi < 8; ++mi){
    int row0 = m0 + wmid*128 + mi*16 + lg*4;
    #pragma unroll
    for (int nj = 0; nj < 4; ++nj){
      int col = n0 + wnid*64 + nj*16 + lrow;
      if constexpr (MODE == 0){
        if (col < 4096){
          #pragma unroll
          for (int r = 0; r < 4; ++r)
            OB[(size_t)(row0 + r)*4096 + col] = f2bf(acc[mi][nj][r]);
        } else {
          int d = col - 4096, hh = d >> 7, dd = d & 127;
          int bb = row0 >> logT;
          int t0 = row0 - (bb << logT);
          ushort4 pk;
          pk.x = f2bf(acc[mi][nj][0]); pk.y = f2bf(acc[mi][nj][1]);
          pk.z = f2bf(acc[mi][nj][2]); pk.w = f2bf(acc[mi][nj][3]);
          *reinterpret_cast<ushort4*>(
              &VT[(((size_t)(bb*16 + hh)*128 + dd) << logT) + t0]) = pk;
        }
      } else {
        #pragma unroll
        for (int r = 0; r < 4; ++r)
          OF[(size_t)(row0 + r)*2048 + col] = acc[mi][nj][r];
      }
    }
  }
  #undef STA8
  #undef STB8
}

// ---------------- fused cross-attention (unchanged from R0) ----------------
template<int SKV, int WARPS, bool WA>
__global__ __launch_bounds__(WARPS*64, 2)
void attn_k(const ushort* __restrict__ qbuf, const ushort* __restrict__ kbuf,
            const ushort* __restrict__ vtb, float* __restrict__ attn,
            ushort* __restrict__ ctx, int TQ)
{
  constexpr int NT = SKV / 32;
  constexpr int NI = 512 / (WARPS*64);
  __shared__ __align__(16) ushort Ks[2][4096];
  __shared__ __align__(16) ushort Vs[2][4096];
  __shared__ __align__(16) float ast[WA ? WARPS*32*36 : 4];
  __shared__ float linv[WARPS*32];
  const int tid = threadIdx.x;
  const int l = tid & 63, wid = tid >> 6;
  const int hi = l >> 5, q = l & 31;
  const int b = blockIdx.z, h = blockIdx.y;
  const int q0 = blockIdx.x*(WARPS*32) + wid*32;
  const ushort* kbase = kbuf + (size_t)b*SKV*4096 + 2048 + h*128;
  const ushort* vbase = vtb + ((size_t)(b*16 + h))*128*SKV;

  b8 qf[8];
  {
    const ushort* qp = qbuf + (size_t)(b*TQ + q0 + q)*4096 + h*128 + hi*8;
    #pragma unroll
    for (int kd = 0; kd < 8; ++kd)
      qf[kd] = *reinterpret_cast<const b8*>(qp + kd*16);
  }

  #define STK(tt, bi) { int S0_ = (tt)*32; _Pragma("unroll") \
    for (int i_ = 0; i_ < NI; ++i_){ \
      int c_ = wid*64 + l + i_*(WARPS*64); int s_ = c_>>4, g_ = c_&15; \
      async16(kbase + (size_t)(S0_+s_)*4096 + (g_^(s_&15))*8, &Ks[bi][c_*8]); } }
  #define STV(tt, bi) { int S0_ = (tt)*32; _Pragma("unroll") \
    for (int i_ = 0; i_ < NI; ++i_){ \
      int c_ = wid*64 + l + i_*(WARPS*64); int d_ = c_>>2, g_ = c_&3; \
      async16(vbase + (size_t)d_*SKV + S0_ + (g_^(d_&3))*8, &Vs[bi][c_*8]); } }

  float mrun = -1e30f, lrun = 0.0f;
  STK(0, 0);
  for (int t = 0; t < NT; ++t){
    __syncthreads();
    if (t+1 < NT) STK(t+1, (t+1)&1);
    f16v s16 = {};
    #pragma unroll
    for (int kd = 0; kd < 8; ++kd){
      int gg = (kd*2 + hi) ^ (q & 15);
      b8 kf = *reinterpret_cast<const b8*>(&Ks[t&1][q*128 + gg*8]);
      s16 = MFMA_32(kf, qf[kd], s16);
    }
    float tm = s16[0];
    #pragma unroll
    for (int r = 1; r < 16; ++r) tm = fmaxf(tm, s16[r]);
    float mnew = fmaxf(mrun, tm);
    float sum = 0.f;
    #pragma unroll
    for (int r = 0; r < 16; ++r) sum += exp2f(s16[r] - mnew);
    lrun = lrun * exp2f(mrun - mnew) + sum;
    mrun = mnew;
  }
  {
    float mo = __shfl_xor(mrun, 32, 64);
    float lo = __shfl_xor(lrun, 32, 64);
    float mf = fmaxf(mrun, mo);
    lrun = lrun * exp2f(mrun - mf) + lo * exp2f(mo - mf);
    mrun = mf;
  }
  float invl = 1.0f / lrun;
  if (hi == 0) linv[wid*32 + q] = invl;
  __syncthreads();
  STK(0, 0); STV(0, 0);

  f16v O[4] = {};
  for (int t = 0; t < NT; ++t){
    __syncthreads();
    if (t+1 < NT){ STK(t+1, (t+1)&1); STV(t+1, (t+1)&1); }
    const int bi = t & 1;
    f16v s16 = {};
    #pragma unroll
    for (int kd = 0; kd < 8; ++kd){
      int gg = (kd*2 + hi) ^ (q & 15);
      b8 kf = *reinterpret_cast<const b8*>(&Ks[bi][q*128 + gg*8]);
      s16 = MFMA_32(kf, qf[kd], s16);
    }
    float e[16];
    #pragma unroll
    for (int r = 0; r < 16; ++r) e[r] = exp2f(s16[r] - mrun);
    if constexpr (WA){
      float* myt = &ast[wid*32*36];
      #pragma unroll
      for (int r = 0; r < 16; ++r){
        int sr = (r&3) + 8*(r>>2) + 4*hi;
        myt[q*36 + sr] = e[r] * invl;
      }
    }
    #pragma unroll
    for (int ks = 0; ks < 2; ++ks){
      const int base = ks*8;
      uint32 A0 = cvtpk(e[base+0], e[base+1]);
      uint32 A1 = cvtpk(e[base+2], e[base+3]);
      uint32 B0 = cvtpk(e[base+4], e[base+5]);
      uint32 B1 = cvtpk(e[base+6], e[base+7]);
      uint32 A0x = (uint32)__shfl_xor((int)A0, 32, 64);
      uint32 A1x = (uint32)__shfl_xor((int)A1, 32, 64);
      uint32 B0x = (uint32)__shfl_xor((int)B0, 32, 64);
      uint32 B1x = (uint32)__shfl_xor((int)B1, 32, 64);
      uint4 ww;
      ww.x = hi ? B0x : A0;
      ww.y = hi ? B1x : A1;
      ww.z = hi ? B0  : A0x;
      ww.w = hi ? B1  : A1x;
      b8 pa = __builtin_bit_cast(b8, ww);
      #pragma unroll
      for (int nb = 0; nb < 4; ++nb){
        int d = nb*32 + q;
        int gg2 = (ks*2 + hi) ^ (d & 3);
        b8 vfr = *reinterpret_cast<const b8*>(&Vs[bi][d*32 + gg2*8]);
        O[nb] = MFMA_32(pa, vfr, O[nb]);
      }
    }
    if constexpr (WA){
      const float* myt = &ast[wid*32*36];
      size_t abase = ((size_t)(b*16 + h)*TQ + q0) * SKV + t*32;
      #pragma unroll
      for (int it = 0; it < 4; ++it){
        int qq = (l >> 3) + it*8;
        float4 vv = *reinterpret_cast<const float4*>(&myt[qq*36 + (l&7)*4]);
        *reinterpret_cast<float4*>(&attn[abase + (size_t)qq*SKV + (l&7)*4]) = vv;
      }
    }
  }
  #pragma unroll
  for (int nb = 0; nb < 4; ++nb){
    #pragma unroll
    for (int r = 0; r < 16; ++r){
      int lq = (r&3) + 8*(r>>2) + 4*hi;
      float val = O[nb][r] * linv[wid*32 + lq];
      ctx[(size_t)(b*TQ + q0 + lq)*2048 + h*128 + nb*32 + q] = f2bf(val);
    }
  }
  #undef STK
  #undef STV
}

// ---------------- host ----------------
extern "C" void kernel_launch(void* const* d_in, const int* in_sizes, int n_in,
                              void* d_out, int out_size, void* d_ws, size_t ws_size,
                              hipStream_t stream)
{
  (void)in_sizes; (void)n_in; (void)out_size; (void)ws_size;
  const float* vfeat = (const float*)d_in[0];
  const float* lfeat = (const float*)d_in[1];
  const float* vpos  = (const float*)d_in[2];
  const float* lpos  = (const float*)d_in[3];
  const float* vw    = (const float*)d_in[4];
  const float* lw    = (const float*)d_in[5];
  const float* w_vq  = (const float*)d_in[6];
  const float* w_vk  = (const float*)d_in[7];
  const float* w_vv  = (const float*)d_in[8];
  const float* w_lq  = (const float*)d_in[9];
  const float* w_lk  = (const float*)d_in[10];
  const float* w_lv  = (const float*)d_in[11];
  const float* w_v2l = (const float*)d_in[12];
  const float* w_l2v = (const float*)d_in[13];
  const float* w_out = (const float*)d_in[14];

  float* out     = (float*)d_out;
  float* fused_o = out;                 // [2,3072,2048]
  float* vis_o   = out + 12582912;      // [2,1024,2048]
  float* lan_o   = out + 16777216;      // [2,2048,2048]
  float* attn_o  = out + 25165824;      // [2,16,1024,2048]

  ushort* ws = (ushort*)d_ws;
  ushort* wcat_v = ws;                        // [6144][2048] bf16
  ushort* wcat_l = wcat_v + 12582912;         // [6144][2048]
  ushort* vnb    = wcat_l + 12582912;         // [2048][2048]
  ushort* lnb    = vnb + 4194304;             // [4096][2048]
  ushort* vqk    = lnb + 8388608;             // [2048][4096]
  ushort* lqk    = vqk + 8388608;             // [4096][4096]
  ushort* vtv    = lqk + 16777216;            // [2,16,128,1024]
  ushort* vtl    = vtv + 4194304;             // [2,16,128,2048]
  ushort* vctx    = wcat_v;                   // overlays
  ushort* lctx    = wcat_v + 4194304;
  ushort* w_v2l_b = wcat_l;
  ushort* w_l2v_b = wcat_l + 4194304;
  ushort* w_out_b = wcat_l + 8388608;

  const float QS = 0.08838834764831845f * 1.4426950408889634f; // SCALE * log2(e)

  {
    CastArgs a;
    a.s[0]=w_vq; a.d[0]=wcat_v;           a.sc[0]=QS;
    a.s[1]=w_vk; a.d[1]=wcat_v+4194304;   a.sc[1]=1.f;
    a.s[2]=w_vv; a.d[2]=wcat_v+8388608;   a.sc[2]=1.f;
    a.s[3]=w_lq; a.d[3]=wcat_l;           a.sc[3]=QS;
    a.s[4]=w_lk; a.d[4]=wcat_l+4194304;   a.sc[4]=1.f;
    a.s[5]=w_lv; a.d[5]=wcat_l+8388608;   a.sc[5]=1.f;
    a.nseg = 6;
    cast_k<<<2048,256,0,stream>>>(a);
  }
  prep_k<<<6144,256,0,stream>>>(vfeat,lfeat,vpos,lpos,vw,lw,vis_o,lan_o,vnb,lnb);
  gemm8_k<0><<<dim3(24,8 ),512,0,stream>>>(vnb,nullptr,wcat_v,vqk,vtv,nullptr,10);
  gemm8_k<0><<<dim3(24,16),512,0,stream>>>(lnb,nullptr,wcat_l,lqk,vtl,nullptr,11);
  {
    CastArgs a;
    a.s[0]=w_v2l; a.d[0]=w_v2l_b; a.sc[0]=1.f;
    a.s[1]=w_l2v; a.d[1]=w_l2v_b; a.sc[1]=1.f;
    a.s[2]=w_out; a.d[2]=w_out_b; a.sc[2]=1.f;
    a.nseg = 3;
    cast_k<<<2048,256,0,stream>>>(a);
  }
  attn_k<2048,4,true ><<<dim3( 8,16,2),256,0,stream>>>(vqk,lqk,vtl,attn_o,vctx,1024);
  attn_k<1024,4,false><<<dim3(16,16,2),256,0,stream>>>(lqk,vqk,vtv,nullptr,lctx,2048);
  gemm_k<1><<<dim3(16,16),256,0,stream>>>(vctx,nullptr,w_v2l_b,vnb,nullptr,vis_o,0);
  gemm_k<1><<<dim3(16,32),256,0,stream>>>(lctx,nullptr,w_l2v_b,lnb,nullptr,lan_o,0);
  gemm8_k<2><<<dim3(8,24),512,0,stream>>>(vnb,lnb,w_out_b,nullptr,nullptr,fused_o,0);
}

// Round 4
// 1108.381 us; speedup vs baseline: 1.0726x; 1.0656x over previous
//
#include <hip/hip_runtime.h>
#include <hip/hip_bf16.h>

// Qwen3VL vision-language cross-attention block, MI355X/gfx950.
// R2: launch fusion for occupancy. QKV (vision+language) = ONE 576-wg 8-phase
// 256^2 GEMM; ctx-proj (vision+language) = ONE 768-wg 128^2 m97 GEMM (3 wg/CU
// restored). Pipeline: cast6 -> prep -> gemm8<0> QKV -> cast3 -> attn v2l ->
// attn l2v -> gemmc ctx(+residual) -> gemm8<2> final.
// (R3 resubmit: R2 never ran — GPU acquisition timeout.)

typedef __bf16 b8 __attribute__((ext_vector_type(8)));
typedef float f4 __attribute__((ext_vector_type(4)));
typedef float f16v __attribute__((ext_vector_type(16)));
typedef unsigned int uint32;

#define MFMA_16(a,b,c) __builtin_amdgcn_mfma_f32_16x16x32_bf16(a,b,c,0,0,0)
#define MFMA_32(a,b,c) __builtin_amdgcn_mfma_f32_32x32x16_bf16(a,b,c,0,0,0)

__device__ __forceinline__ ushort f2bf(float f){
  uint32 u = __float_as_uint(f);
  return (ushort)((u + 0x7FFFu + ((u >> 16) & 1u)) >> 16);
}

__device__ __forceinline__ void async16(const void* g, void* l){
  __builtin_amdgcn_global_load_lds(
      (__attribute__((address_space(1))) void*)(g),
      (__attribute__((address_space(3))) void*)(l), 16, 0, 0);
}

__device__ __forceinline__ uint32 cvtpk(float a, float b){
  uint32 r;
  asm("v_cvt_pk_bf16_f32 %0, %1, %2" : "=v"(r) : "v"(a), "v"(b));
  return r;
}

// fused-concat row remap for the final GEMM's A (vnb rows 0-2047 | lnb 2048-6143)
__device__ __forceinline__ int fconcat(int f){
  return (f < 1024) ? f : (f < 3072) ? f + 1024 : (f < 4096) ? f - 2048 : f;
}

// ---------------- weight cast (f32 -> bf16, optional scale) ----------------
struct CastArgs { const float* s[6]; ushort* d[6]; float sc[6]; int nseg; };

__global__ __launch_bounds__(256)
void cast_k(CastArgs a){
  int n = a.nseg << 20;
  for (int i = blockIdx.x*blockDim.x + threadIdx.x; i < n; i += gridDim.x*blockDim.x){
    int seg = i >> 20, off = i & 1048575;
    float4 v = reinterpret_cast<const float4*>(a.s[seg])[off];
    float sc = a.sc[seg];
    ushort4 o;
    o.x = f2bf(v.x*sc); o.y = f2bf(v.y*sc); o.z = f2bf(v.z*sc); o.w = f2bf(v.w*sc);
    reinterpret_cast<ushort4*>(a.d[seg])[off] = o;
  }
}

// ---------------- pos-embed add + RMSNorm ----------------
__global__ __launch_bounds__(256)
void prep_k(const float* __restrict__ vfeat, const float* __restrict__ lfeat,
            const float* __restrict__ vpos, const float* __restrict__ lpos,
            const float* __restrict__ vw, const float* __restrict__ lw,
            float* __restrict__ vfo, float* __restrict__ lfo,
            ushort* __restrict__ vnb, ushort* __restrict__ lnb)
{
  const int row = blockIdx.x;
  const float *src, *pos, *w;
  float* fo; ushort* nb;
  if (row < 2048){
    src = vfeat + (size_t)row*2048; pos = vpos + (size_t)(row & 1023)*2048;
    w = vw; fo = vfo + (size_t)row*2048; nb = vnb + (size_t)row*2048;
  } else {
    int r = row - 2048;
    src = lfeat + (size_t)r*2048; pos = lpos + (size_t)(r & 2047)*2048;
    w = lw; fo = lfo + (size_t)r*2048; nb = lnb + (size_t)r*2048;
  }
  const int t = threadIdx.x;
  float4 a0 = reinterpret_cast<const float4*>(src)[t];
  float4 p0 = reinterpret_cast<const float4*>(pos)[t];
  float4 a1 = reinterpret_cast<const float4*>(src)[t+256];
  float4 p1 = reinterpret_cast<const float4*>(pos)[t+256];
  a0.x += p0.x; a0.y += p0.y; a0.z += p0.z; a0.w += p0.w;
  a1.x += p1.x; a1.y += p1.y; a1.z += p1.z; a1.w += p1.w;
  float ss = a0.x*a0.x + a0.y*a0.y + a0.z*a0.z + a0.w*a0.w
           + a1.x*a1.x + a1.y*a1.y + a1.z*a1.z + a1.w*a1.w;
  #pragma unroll
  for (int o = 32; o > 0; o >>= 1) ss += __shfl_xor(ss, o, 64);
  __shared__ float red[4];
  if ((t & 63) == 0) red[t >> 6] = ss;
  __syncthreads();
  float rs = rsqrtf((red[0]+red[1]+red[2]+red[3]) * (1.0f/2048.0f) + 1e-6f);
  reinterpret_cast<float4*>(fo)[t]     = a0;
  reinterpret_cast<float4*>(fo)[t+256] = a1;
  float4 w0 = reinterpret_cast<const float4*>(w)[t];
  float4 w1 = reinterpret_cast<const float4*>(w)[t+256];
  ushort4 o0, o1;
  o0.x = f2bf(a0.x*rs*w0.x); o0.y = f2bf(a0.y*rs*w0.y);
  o0.z = f2bf(a0.z*rs*w0.z); o0.w = f2bf(a0.w*rs*w0.w);
  o1.x = f2bf(a1.x*rs*w1.x); o1.y = f2bf(a1.y*rs*w1.y);
  o1.z = f2bf(a1.z*rs*w1.z); o1.w = f2bf(a1.w*rs*w1.w);
  reinterpret_cast<ushort4*>(nb)[t]     = o0;
  reinterpret_cast<ushort4*>(nb)[t+256] = o1;
}

// -------- fused ctx-proj GEMM, 128x128 m97 structure, 768 wgs (3/CU) --------
// A = contiguous 6144 rows (vctx | lctx). by' < 16 -> vision (W_v2l, vis_o,
// vnb); else language. f32 out = acc + OF (residual in d_out), bf16 mirror.
__global__ __launch_bounds__(256, 3)
void gemmc_k(const ushort* __restrict__ A,
             const ushort* __restrict__ Wv, const ushort* __restrict__ Wl,
             ushort* __restrict__ OBv, ushort* __restrict__ OBl,
             float* __restrict__ OFv, float* __restrict__ OFl)
{
  __shared__ __align__(16) ushort As[4096];
  __shared__ __align__(16) ushort Bs[4096];
  const int tid = threadIdx.x;
  const int l = tid & 63, wid = tid >> 6;
  const int wm = (wid >> 1) * 64, wn = (wid & 1) * 64;
  // bijective XCD swizzle over 768 wgs
  const int wg = blockIdx.y*16 + blockIdx.x;
  const int swz = (wg & 7)*96 + (wg >> 3);
  const int byp = swz >> 4, bxp = swz & 15;
  const bool lang = byp >= 16;
  const int m0g = byp * 128;                       // A row base (global 0..6143)
  const int m0l = (lang ? byp - 16 : byp) * 128;   // output row base (per side)
  const int n0 = bxp * 128;
  const ushort* W = lang ? Wl : Wv;
  ushort* OB = lang ? OBl : OBv;
  float*  OF = lang ? OFl : OFv;
  const int lr = l & 15, lk = l >> 4;
  f4 acc[4][4] = {};
  for (int kt = 0; kt < 2048; kt += 32) {
    #pragma unroll
    for (int i = 0; i < 2; ++i){
      int c = wid*64 + l + i*256;
      int row = c >> 2, kc = (c & 3) * 8;
      async16(A + (size_t)(m0g + row)*2048 + kt + kc, &As[c*8]);
      async16(W + (size_t)(n0 + row)*2048 + kt + kc, &Bs[c*8]);
    }
    __syncthreads();
    b8 af[4], bfr[4];
    #pragma unroll
    for (int i = 0; i < 4; ++i)
      af[i] = *reinterpret_cast<const b8*>(&As[(wm + i*16 + lr)*32 + lk*8]);
    #pragma unroll
    for (int j = 0; j < 4; ++j)
      bfr[j] = *reinterpret_cast<const b8*>(&Bs[(wn + j*16 + lr)*32 + lk*8]);
    #pragma unroll
    for (int i = 0; i < 4; ++i)
      #pragma unroll
      for (int j = 0; j < 4; ++j)
        acc[i][j] = MFMA_16(af[i], bfr[j], acc[i][j]);
    __syncthreads();
  }
  #pragma unroll
  for (int i = 0; i < 4; ++i){
    int row0 = m0l + wm + i*16 + lk*4;
    #pragma unroll
    for (int j = 0; j < 4; ++j){
      int col = n0 + wn + j*16 + lr;
      #pragma unroll
      for (int r = 0; r < 4; ++r){
        size_t idx = (size_t)(row0 + r)*2048 + col;
        float v = acc[i][j][r] + OF[idx];
        OF[idx] = v;
        OB[idx] = f2bf(v);
      }
    }
  }
}

// ---------------- 256x256 8-phase GEMM (T1+T2+T3+T4+T5) ----------------
// MODE 0: fused QKV. A = contiguous 6144 rows (vnb | lnb). m-tiles 0-7 vision
//   (Wv, OBv/vqk, VTv, logT=10), 8-23 language. Epilogue: Q|K bf16 cols<4096,
//   V transposed into VT[b,h,d,t].
// MODE 2: final proj. A rows = batch-concat remap (fconcat) over vnb|lnb,
//   W = Wv, f32 out only.
template<int MODE>
__global__ __launch_bounds__(512, 2)
void gemm8_k(const ushort* __restrict__ A,
             const ushort* __restrict__ Wv, const ushort* __restrict__ Wl,
             ushort* __restrict__ OBv, ushort* __restrict__ OBl,
             ushort* __restrict__ VTv, ushort* __restrict__ VTl,
             float* __restrict__ OF)
{
  __shared__ __align__(16) ushort Ls[65536];   // 128 KiB
  const int tid = threadIdx.x;
  const int l = tid & 63, wid = tid >> 6;
  const int wmid = wid >> 2, wnid = wid & 3;
  const int lrow = l & 15, lg = l >> 4, lx = l & 7;

  // T1: bijective XCD swizzle (nwg % 8 == 0 for both grids)
  const int nbx = gridDim.x;
  const int nwg = nbx * gridDim.y;
  const int wg  = blockIdx.y*nbx + blockIdx.x;
  const int swz = (wg & 7)*(nwg >> 3) + (wg >> 3);
  const int mt = swz / nbx, nt = swz % nbx;
  const int n0 = nt * 256;
  const int m0g = mt * 256;                // A row base (global)
  const ushort* W;
  ushort* OB; ushort* VT;
  int logT, m0l;
  if constexpr (MODE == 0){
    const bool lang = mt >= 8;
    W = lang ? Wl : Wv;
    OB = lang ? OBl : OBv;
    VT = lang ? VTl : VTv;
    logT = lang ? 11 : 10;
    m0l = lang ? (mt - 8)*256 : m0g;
  } else {
    W = Wv; OB = nullptr; VT = nullptr; logT = 0; m0l = m0g;
  }

  // per-thread stage sources (chunk c = tid + i*512; r = c>>3, gs = c&7)
  const ushort* srcA[2][2];
  const ushort* srcB[2][2];
  int ldsOff[2];
  #pragma unroll
  for (int i = 0; i < 2; ++i){
    int c = tid + i*512;
    int r = c >> 3, gs = c & 7;
    int scol = (gs ^ (r & 7)) * 8;     // pre-swizzled source granule
    ldsOff[i] = c * 8;
    #pragma unroll
    for (int hh = 0; hh < 2; ++hh){
      int growA = m0g + hh*128 + r;
      if constexpr (MODE == 2) growA = fconcat(growA);
      srcA[hh][i] = A + (size_t)growA*2048 + scol;
      srcB[hh][i] = W + (size_t)(n0 + hh*128 + r)*2048 + scol;
    }
  }

  #define STA8(hh, tt) { int bo_ = ((tt)&1)*32768; _Pragma("unroll") \
    for (int i_ = 0; i_ < 2; ++i_) \
      async16(srcA[hh][i_] + (tt)*64, &Ls[bo_ + (hh)*8192 + ldsOff[i_]]); }
  #define STB8(hh, tt) { int bo_ = ((tt)&1)*32768; _Pragma("unroll") \
    for (int i_ = 0; i_ < 2; ++i_) \
      async16(srcB[hh][i_] + (tt)*64, &Ls[bo_ + 16384 + (hh)*8192 + ldsOff[i_]]); }

  // read-side addressing (swizzle undone: g ^ lx)
  const int aBase = wmid*8192 + lrow*64;
  const int bBase = 16384 + (wnid>>1)*8192 + (wnid&1)*4096 + lrow*64;
  int gsw[2];
  gsw[0] = ((0*4 + lg) ^ lx) * 8;
  gsw[1] = ((1*4 + lg) ^ lx) * 8;

  constexpr int NT = 32;   // K = 2048 / BK = 64
  STB8(0,0); STB8(1,0); STA8(0,0); STA8(1,0); STB8(0,1); STB8(1,1); STA8(0,1);
  asm volatile("s_waitcnt vmcnt(6)" ::: "memory");
  __builtin_amdgcn_s_barrier();

  f4 acc[8][4] = {};
  b8 afr[4][2], b0r[2][2], b1r[2][2];

  for (int t = 0; t < NT; ++t){
    const ushort* Lb = &Ls[(t & 1) * 32768];
    // phase 0: read A-half rows 0-63 + B rows 0-31, stage A1(t+1), MFMA Q0
    #pragma unroll
    for (int mi = 0; mi < 4; ++mi)
      #pragma unroll
      for (int kk = 0; kk < 2; ++kk)
        afr[mi][kk] = *reinterpret_cast<const b8*>(&Lb[aBase + mi*1024 + gsw[kk]]);
    #pragma unroll
    for (int nj = 0; nj < 2; ++nj)
      #pragma unroll
      for (int kk = 0; kk < 2; ++kk)
        b0r[nj][kk] = *reinterpret_cast<const b8*>(&Lb[bBase + nj*1024 + gsw[kk]]);
    if (t+1 < NT) STA8(1, t+1);
    __builtin_amdgcn_s_barrier();
    asm volatile("s_waitcnt lgkmcnt(0)" ::: "memory");
    __builtin_amdgcn_s_setprio(1);
    #pragma unroll
    for (int mi = 0; mi < 4; ++mi)
      #pragma unroll
      for (int nj = 0; nj < 2; ++nj)
        #pragma unroll
        for (int kk = 0; kk < 2; ++kk)
          acc[mi][nj] = MFMA_16(afr[mi][kk], b0r[nj][kk], acc[mi][nj]);
    __builtin_amdgcn_s_setprio(0);
    __builtin_amdgcn_s_barrier();
    // phase 1: read B rows 32-63, MFMA Q1
    #pragma unroll
    for (int nj = 0; nj < 2; ++nj)
      #pragma unroll
      for (int kk = 0; kk < 2; ++kk)
        b1r[nj][kk] = *reinterpret_cast<const b8*>(&Lb[bBase + (2+nj)*1024 + gsw[kk]]);
    __builtin_amdgcn_s_barrier();
    asm volatile("s_waitcnt lgkmcnt(0)" ::: "memory");
    __builtin_amdgcn_s_setprio(1);
    #pragma unroll
    for (int mi = 0; mi < 4; ++mi)
      #pragma unroll
      for (int nj = 0; nj < 2; ++nj)
        #pragma unroll
        for (int kk = 0; kk < 2; ++kk)
          acc[mi][2+nj] = MFMA_16(afr[mi][kk], b1r[nj][kk], acc[mi][2+nj]);
    __builtin_amdgcn_s_setprio(0);
    __builtin_amdgcn_s_barrier();
    // phase 2: read A-half rows 64-127, stage B0(t+2), MFMA Q2
    #pragma unroll
    for (int mi = 0; mi < 4; ++mi)
      #pragma unroll
      for (int kk = 0; kk < 2; ++kk)
        afr[mi][kk] = *reinterpret_cast<const b8*>(&Lb[aBase + 4096 + mi*1024 + gsw[kk]]);
    if (t+2 < NT) STB8(0, t+2);
    __builtin_amdgcn_s_barrier();
    asm volatile("s_waitcnt lgkmcnt(0)" ::: "memory");
    __builtin_amdgcn_s_setprio(1);
    #pragma unroll
    for (int mi = 0; mi < 4; ++mi)
      #pragma unroll
      for (int nj = 0; nj < 2; ++nj)
        #pragma unroll
        for (int kk = 0; kk < 2; ++kk)
          acc[4+mi][nj] = MFMA_16(afr[mi][kk], b0r[nj][kk], acc[4+mi][nj]);
    __builtin_amdgcn_s_setprio(0);
    __builtin_amdgcn_s_barrier();
    // phase 3: stage B1(t+2)+A0(t+2), MFMA Q3, counted vmcnt
    if (t+2 < NT){ STB8(1, t+2); STA8(0, t+2); }
    __builtin_amdgcn_s_barrier();
    __builtin_amdgcn_s_setprio(1);
    #pragma unroll
    for (int mi = 0; mi < 4; ++mi)
      #pragma unroll
      for (int nj = 0; nj < 2; ++nj)
        #pragma unroll
        for (int kk = 0; kk < 2; ++kk)
          acc[4+mi][2+nj] = MFMA_16(afr[mi][kk], b1r[nj][kk], acc[4+mi][2+nj]);
    __builtin_amdgcn_s_setprio(0);
    if (t+2 < NT){ asm volatile("s_waitcnt vmcnt(6)" ::: "memory"); }
    else         { asm volatile("s_waitcnt vmcnt(0)" ::: "memory"); }
    __builtin_amdgcn_s_barrier();
  }

  // epilogue
  #pragma unroll
  for (int mi = 0; mi < 8; ++mi){
    int row0 = m0l + wmid*128 + mi*16 + lg*4;
    #pragma unroll
    for (int nj = 0; nj < 4; ++nj){
      int col = n0 + wnid*64 + nj*16 + lrow;
      if constexpr (MODE == 0){
        if (col < 4096){
          #pragma unroll
          for (int r = 0; r < 4; ++r)
            OB[(size_t)(row0 + r)*4096 + col] = f2bf(acc[mi][nj][r]);
        } else {
          int d = col - 4096, hh = d >> 7, dd = d & 127;
          int bb = row0 >> logT;
          int t0 = row0 - (bb << logT);
          ushort4 pk;
          pk.x = f2bf(acc[mi][nj][0]); pk.y = f2bf(acc[mi][nj][1]);
          pk.z = f2bf(acc[mi][nj][2]); pk.w = f2bf(acc[mi][nj][3]);
          *reinterpret_cast<ushort4*>(
              &VT[(((size_t)(bb*16 + hh)*128 + dd) << logT) + t0]) = pk;
        }
      } else {
        #pragma unroll
        for (int r = 0; r < 4; ++r)
          OF[(size_t)(row0 + r)*2048 + col] = acc[mi][nj][r];
      }
    }
  }
  #undef STA8
  #undef STB8
}

// ---------------- fused cross-attention (unchanged) ----------------
template<int SKV, int WARPS, bool WA>
__global__ __launch_bounds__(WARPS*64, 2)
void attn_k(const ushort* __restrict__ qbuf, const ushort* __restrict__ kbuf,
            const ushort* __restrict__ vtb, float* __restrict__ attn,
            ushort* __restrict__ ctx, int TQ)
{
  constexpr int NT = SKV / 32;
  constexpr int NI = 512 / (WARPS*64);
  __shared__ __align__(16) ushort Ks[2][4096];
  __shared__ __align__(16) ushort Vs[2][4096];
  __shared__ __align__(16) float ast[WA ? WARPS*32*36 : 4];
  __shared__ float linv[WARPS*32];
  const int tid = threadIdx.x;
  const int l = tid & 63, wid = tid >> 6;
  const int hi = l >> 5, q = l & 31;
  const int b = blockIdx.z, h = blockIdx.y;
  const int q0 = blockIdx.x*(WARPS*32) + wid*32;
  const ushort* kbase = kbuf + (size_t)b*SKV*4096 + 2048 + h*128;
  const ushort* vbase = vtb + ((size_t)(b*16 + h))*128*SKV;

  b8 qf[8];
  {
    const ushort* qp = qbuf + (size_t)(b*TQ + q0 + q)*4096 + h*128 + hi*8;
    #pragma unroll
    for (int kd = 0; kd < 8; ++kd)
      qf[kd] = *reinterpret_cast<const b8*>(qp + kd*16);
  }

  #define STK(tt, bi) { int S0_ = (tt)*32; _Pragma("unroll") \
    for (int i_ = 0; i_ < NI; ++i_){ \
      int c_ = wid*64 + l + i_*(WARPS*64); int s_ = c_>>4, g_ = c_&15; \
      async16(kbase + (size_t)(S0_+s_)*4096 + (g_^(s_&15))*8, &Ks[bi][c_*8]); } }
  #define STV(tt, bi) { int S0_ = (tt)*32; _Pragma("unroll") \
    for (int i_ = 0; i_ < NI; ++i_){ \
      int c_ = wid*64 + l + i_*(WARPS*64); int d_ = c_>>2, g_ = c_&3; \
      async16(vbase + (size_t)d_*SKV + S0_ + (g_^(d_&3))*8, &Vs[bi][c_*8]); } }

  float mrun = -1e30f, lrun = 0.0f;
  STK(0, 0);
  for (int t = 0; t < NT; ++t){
    __syncthreads();
    if (t+1 < NT) STK(t+1, (t+1)&1);
    f16v s16 = {};
    #pragma unroll
    for (int kd = 0; kd < 8; ++kd){
      int gg = (kd*2 + hi) ^ (q & 15);
      b8 kf = *reinterpret_cast<const b8*>(&Ks[t&1][q*128 + gg*8]);
      s16 = MFMA_32(kf, qf[kd], s16);
    }
    float tm = s16[0];
    #pragma unroll
    for (int r = 1; r < 16; ++r) tm = fmaxf(tm, s16[r]);
    float mnew = fmaxf(mrun, tm);
    float sum = 0.f;
    #pragma unroll
    for (int r = 0; r < 16; ++r) sum += exp2f(s16[r] - mnew);
    lrun = lrun * exp2f(mrun - mnew) + sum;
    mrun = mnew;
  }
  {
    float mo = __shfl_xor(mrun, 32, 64);
    float lo = __shfl_xor(lrun, 32, 64);
    float mf = fmaxf(mrun, mo);
    lrun = lrun * exp2f(mrun - mf) + lo * exp2f(mo - mf);
    mrun = mf;
  }
  float invl = 1.0f / lrun;
  if (hi == 0) linv[wid*32 + q] = invl;
  __syncthreads();
  STK(0, 0); STV(0, 0);

  f16v O[4] = {};
  for (int t = 0; t < NT; ++t){
    __syncthreads();
    if (t+1 < NT){ STK(t+1, (t+1)&1); STV(t+1, (t+1)&1); }
    const int bi = t & 1;
    f16v s16 = {};
    #pragma unroll
    for (int kd = 0; kd < 8; ++kd){
      int gg = (kd*2 + hi) ^ (q & 15);
      b8 kf = *reinterpret_cast<const b8*>(&Ks[bi][q*128 + gg*8]);
      s16 = MFMA_32(kf, qf[kd], s16);
    }
    float e[16];
    #pragma unroll
    for (int r = 0; r < 16; ++r) e[r] = exp2f(s16[r] - mrun);
    if constexpr (WA){
      float* myt = &ast[wid*32*36];
      #pragma unroll
      for (int r = 0; r < 16; ++r){
        int sr = (r&3) + 8*(r>>2) + 4*hi;
        myt[q*36 + sr] = e[r] * invl;
      }
    }
    #pragma unroll
    for (int ks = 0; ks < 2; ++ks){
      const int base = ks*8;
      uint32 A0 = cvtpk(e[base+0], e[base+1]);
      uint32 A1 = cvtpk(e[base+2], e[base+3]);
      uint32 B0 = cvtpk(e[base+4], e[base+5]);
      uint32 B1 = cvtpk(e[base+6], e[base+7]);
      uint32 A0x = (uint32)__shfl_xor((int)A0, 32, 64);
      uint32 A1x = (uint32)__shfl_xor((int)A1, 32, 64);
      uint32 B0x = (uint32)__shfl_xor((int)B0, 32, 64);
      uint32 B1x = (uint32)__shfl_xor((int)B1, 32, 64);
      uint4 ww;
      ww.x = hi ? B0x : A0;
      ww.y = hi ? B1x : A1;
      ww.z = hi ? B0  : A0x;
      ww.w = hi ? B1  : A1x;
      b8 pa = __builtin_bit_cast(b8, ww);
      #pragma unroll
      for (int nb = 0; nb < 4; ++nb){
        int d = nb*32 + q;
        int gg2 = (ks*2 + hi) ^ (d & 3);
        b8 vfr = *reinterpret_cast<const b8*>(&Vs[bi][d*32 + gg2*8]);
        O[nb] = MFMA_32(pa, vfr, O[nb]);
      }
    }
    if constexpr (WA){
      const float* myt = &ast[wid*32*36];
      size_t abase = ((size_t)(b*16 + h)*TQ + q0) * SKV + t*32;
      #pragma unroll
      for (int it = 0; it < 4; ++it){
        int qq = (l >> 3) + it*8;
        float4 vv = *reinterpret_cast<const float4*>(&myt[qq*36 + (l&7)*4]);
        *reinterpret_cast<float4*>(&attn[abase + (size_t)qq*SKV + (l&7)*4]) = vv;
      }
    }
  }
  #pragma unroll
  for (int nb = 0; nb < 4; ++nb){
    #pragma unroll
    for (int r = 0; r < 16; ++r){
      int lq = (r&3) + 8*(r>>2) + 4*hi;
      float val = O[nb][r] * linv[wid*32 + lq];
      ctx[(size_t)(b*TQ + q0 + lq)*2048 + h*128 + nb*32 + q] = f2bf(val);
    }
  }
  #undef STK
  #undef STV
}

// ---------------- host ----------------
extern "C" void kernel_launch(void* const* d_in, const int* in_sizes, int n_in,
                              void* d_out, int out_size, void* d_ws, size_t ws_size,
                              hipStream_t stream)
{
  (void)in_sizes; (void)n_in; (void)out_size; (void)ws_size;
  const float* vfeat = (const float*)d_in[0];
  const float* lfeat = (const float*)d_in[1];
  const float* vpos  = (const float*)d_in[2];
  const float* lpos  = (const float*)d_in[3];
  const float* vw    = (const float*)d_in[4];
  const float* lw    = (const float*)d_in[5];
  const float* w_vq  = (const float*)d_in[6];
  const float* w_vk  = (const float*)d_in[7];
  const float* w_vv  = (const float*)d_in[8];
  const float* w_lq  = (const float*)d_in[9];
  const float* w_lk  = (const float*)d_in[10];
  const float* w_lv  = (const float*)d_in[11];
  const float* w_v2l = (const float*)d_in[12];
  const float* w_l2v = (const float*)d_in[13];
  const float* w_out = (const float*)d_in[14];

  float* out     = (float*)d_out;
  float* fused_o = out;                 // [2,3072,2048]
  float* vis_o   = out + 12582912;      // [2,1024,2048]
  float* lan_o   = out + 16777216;      // [2,2048,2048]
  float* attn_o  = out + 25165824;      // [2,16,1024,2048]

  ushort* ws = (ushort*)d_ws;
  ushort* wcat_v = ws;                        // [6144][2048] bf16
  ushort* wcat_l = wcat_v + 12582912;         // [6144][2048]
  ushort* vnb    = wcat_l + 12582912;         // [2048][2048]  (lnb adjacent)
  ushort* lnb    = vnb + 4194304;             // [4096][2048]
  ushort* vqk    = lnb + 8388608;             // [2048][4096]
  ushort* lqk    = vqk + 8388608;             // [4096][4096]
  ushort* vtv    = lqk + 16777216;            // [2,16,128,1024]
  ushort* vtl    = vtv + 4194304;             // [2,16,128,2048]
  ushort* vctx    = wcat_v;                   // overlays (vctx|lctx contiguous)
  ushort* lctx    = wcat_v + 4194304;
  ushort* w_v2l_b = wcat_l;
  ushort* w_l2v_b = wcat_l + 4194304;
  ushort* w_out_b = wcat_l + 8388608;

  const float QS = 0.08838834764831845f * 1.4426950408889634f; // SCALE * log2(e)

  {
    CastArgs a;
    a.s[0]=w_vq; a.d[0]=wcat_v;           a.sc[0]=QS;
    a.s[1]=w_vk; a.d[1]=wcat_v+4194304;   a.sc[1]=1.f;
    a.s[2]=w_vv; a.d[2]=wcat_v+8388608;   a.sc[2]=1.f;
    a.s[3]=w_lq; a.d[3]=wcat_l;           a.sc[3]=QS;
    a.s[4]=w_lk; a.d[4]=wcat_l+4194304;   a.sc[4]=1.f;
    a.s[5]=w_lv; a.d[5]=wcat_l+8388608;   a.sc[5]=1.f;
    a.nseg = 6;
    cast_k<<<2048,256,0,stream>>>(a);
  }
  prep_k<<<6144,256,0,stream>>>(vfeat,lfeat,vpos,lpos,vw,lw,vis_o,lan_o,vnb,lnb);
  // fused QKV: 24 n-tiles x 24 m-tiles (8 vision + 16 language) = 576 wgs
  gemm8_k<0><<<dim3(24,24),512,0,stream>>>(vnb, wcat_v, wcat_l,
                                           vqk, lqk, vtv, vtl, nullptr);
  {
    CastArgs a;
    a.s[0]=w_v2l; a.d[0]=w_v2l_b; a.sc[0]=1.f;
    a.s[1]=w_l2v; a.d[1]=w_l2v_b; a.sc[1]=1.f;
    a.s[2]=w_out; a.d[2]=w_out_b; a.sc[2]=1.f;
    a.nseg = 3;
    cast_k<<<2048,256,0,stream>>>(a);
  }
  attn_k<2048,4,true ><<<dim3( 8,16,2),256,0,stream>>>(vqk,lqk,vtl,attn_o,vctx,1024);
  attn_k<1024,4,false><<<dim3(16,16,2),256,0,stream>>>(lqk,vqk,vtv,nullptr,lctx,2048);
  // fused ctx proj: 16 n-tiles x 48 m-tiles (16 vision + 32 language) = 768 wgs
  gemmc_k<<<dim3(16,48),256,0,stream>>>(vctx, w_v2l_b, w_l2v_b,
                                        vnb, lnb, vis_o, lan_o);
  gemm8_k<2><<<dim3(8,24),512,0,stream>>>(vnb, w_out_b, nullptr,
                                          nullptr, nullptr, nullptr, nullptr, fused_o);
}